// Round 3
// baseline (173.930 us; speedup 1.0000x reference)
//
#include <hip/hip_runtime.h>
#include <cstdint>

#define BB 2
#define NN 16384
#define MM 4096
#define CF 256
#define CT 128
#define CP 64

// ======================= kernel 1: 3-NN -> workspace =======================
// Proven bit-exact scan (pre-doubled refs, strict-< index network, med3 value
// network, tau-pruned wave-uniform branchy update). Round-3 changes:
//  - 16 lanes/query, NPB 32 -> grid 2048 blocks -> 32 waves/CU reachable
//    (round 2 measured Occupancy 37%: grid 512 capped at 16 waves/CU).
//  - 2 refs per __any gate (e, e+16): halves branch/loop bookkeeping; body
//    applies the SAME exact update sequentially (a before b, ascending j),
//    so the first-seen tie rule and pruning exactness are unchanged.
#define TPB1 512
#define NPB1 32
#define CHUNK 2048

__global__ __launch_bounds__(TPB1, 8) void knn_kernel(
    const float* __restrict__ coords,      // [B,N,3]
    const float* __restrict__ ref_coords,  // [B,M,3]
    int4* __restrict__ wsI,                // [B,N] {i0,i1,i2,-}
    float4* __restrict__ wsW)              // [B,N] {w0,w1,w2,-}
{
#pragma clang fp contract(off)
    __shared__ float4 refs[CHUNK];      // 32 KB (2x, 2y, 2z, rr)

    const int tid = threadIdx.x;
    const int b   = blockIdx.y;
    const int n0  = blockIdx.x * NPB1;

    const int pl = tid >> 4;            // point-in-block 0..31
    const int s  = tid & 15;            // sub-lane 0..15
    const int n  = n0 + pl;

    const float* cp = coords + ((size_t)b * NN + n) * 3;
    const float cx = cp[0];
    const float cy = cp[1];
    const float cz = cp[2];
    const float cc = (cx * cx + cy * cy) + cz * cz;   // numpy sum order

    float d0 = INFINITY, d1 = INFINITY, d2v = INFINITY;
    int   i0 = 0, i1 = 0, i2 = 0;
    float tau = INFINITY;               // group pruning threshold
    float thr = INFINITY;               // min(d2v, tau)

    const float* rc = ref_coords + (size_t)b * MM * 3;

    // exact top-3 update, identical to the round-0 proven network
    auto upd = [&](float dd, int j) {
        const bool l2 = dd < d2v;
        const bool l1 = dd < d1;
        const bool l0 = dd < d0;
        i2 = l2 ? (l1 ? i1 : j) : i2;
        i1 = l1 ? (l0 ? i0 : j) : i1;
        i0 = l0 ? j : i0;
        const float n2  = __builtin_amdgcn_fmed3f(dd, d1, d2v);
        const float n1  = __builtin_amdgcn_fmed3f(dd, d0, d1);
        const float nv0 = fminf(dd, d0);
        d2v = n2; d1 = n1; d0 = nv0;
    };

    for (int ch = 0; ch < MM / CHUNK; ++ch) {
        __syncthreads();                 // refs[] reuse guard
        for (int e = tid; e < CHUNK; e += TPB1) {
            const int j = ch * CHUNK + e;
            const float x = rc[3 * j + 0];
            const float y = rc[3 * j + 1];
            const float z = rc[3 * j + 2];
            // rr from ORIGINAL coords (numpy order); xyz pre-doubled (exact)
            refs[e] = make_float4(x + x, y + y, z + z, (x * x + y * y) + z * z);
        }
        __syncthreads();

        const int jbase = ch * CHUNK;
        // per-lane elements e = s + k*16, k = 0..127, processed 2 per iter;
        // segments of 32 elements between tau refreshes (as round 2)
        for (int seg = 0; seg < CHUNK / (16 * 32); ++seg) {
            #pragma unroll
            for (int t = 0; t < 16; ++t) {
                const int ea = s + ((seg * 32 + t * 2) << 4);
                const float4 ra = refs[ea];
                const float4 rb = refs[ea + 16];
                const float dot2a = (cx * ra.x + cy * ra.y) + cz * ra.z;
                const float dda   = (cc + ra.w) - dot2a;     // == numpy d2
                const float dot2b = (cx * rb.x + cy * rb.y) + cz * rb.z;
                const float ddb   = (cc + rb.w) - dot2b;
                if (__any(fminf(dda, ddb) < thr)) {
                    const int ja = jbase + ea;
                    upd(dda, ja);          // lower j first: tie rule kept
                    upd(ddb, ja + 16);
                    thr = fminf(d2v, tau);
                }
            }
            // refresh tau = min of the 16 lanes' (same query) d2v
            float tt = d2v;
            tt = fminf(tt, __shfl_xor(tt, 1, 64));
            tt = fminf(tt, __shfl_xor(tt, 2, 64));
            tt = fminf(tt, __shfl_xor(tt, 4, 64));
            tt = fminf(tt, __shfl_xor(tt, 8, 64));
            tau = tt;
            thr = fminf(d2v, tau);
        }
    }

    // lexicographic (d, idx) insert: lower index wins exact ties (stable top_k)
    auto ins = [&](float e, int f) {
        const bool l2 = (e < d2v) || (e == d2v && f < i2);
        const bool l1 = (e < d1)  || (e == d1  && f < i1);
        const bool l0 = (e < d0)  || (e == d0  && f < i0);
        d2v = l2 ? (l1 ? d1 : e) : d2v;  i2 = l2 ? (l1 ? i1 : f) : i2;
        d1  = l1 ? (l0 ? d0 : e) : d1;   i1 = l1 ? (l0 ? i0 : f) : i1;
        d0  = l0 ? e : d0;               i0 = l0 ? f : i0;
    };

    // butterfly across the 16 sub-lanes (xor<16 stays in-group, in-wave)
    for (int off = 1; off < 16; off <<= 1) {
        const float e0 = __shfl_xor(d0,  off, 64);
        const float e1 = __shfl_xor(d1,  off, 64);
        const float e2 = __shfl_xor(d2v, off, 64);
        const int   f0 = __shfl_xor(i0,  off, 64);
        const int   f1 = __shfl_xor(i1,  off, 64);
        const int   f2 = __shfl_xor(i2,  off, 64);
        ins(e0, f0);
        ins(e1, f1);
        ins(e2, f2);
    }

    if (s == 0) {
        float w0 = 1.0f / (d0  + 1e-8f);     // IEEE divs, numpy order
        float w1 = 1.0f / (d1  + 1e-8f);
        float w2 = 1.0f / (d2v + 1e-8f);
        const float sum = (w0 + w1) + w2;
        wsI[(size_t)b * NN + n] = make_int4(i0, i1, i2, 0);
        wsW[(size_t)b * NN + n] = make_float4(w0 / sum, w1 / sum, w2 / sum, 0.0f);
    }
}

// ===================== kernel 2: row-staged interpolation ====================
// Round-3 changes vs round 2:
//  - 2 rows per block (all class/batch boundaries even -> uniform b per
//    block): halves the ~400 MB of redundant idx/w L2 re-reads.
//  - software-pipelined ws loads (prefetch next iter's int4/float4) to hide
//    the ~200-cycle L2 latency that serialized each gather iteration.
// Same fma ordering (contract off) -> bit-identical interpolation.
#define TPB2 512
#define NIB  (BB * (CF + CT) / 2)   // 384 interp blocks (2 rows each)
#define NCB  32                     // copy blocks (4 pf rows each)

__global__ __launch_bounds__(TPB2, 8) void interp_kernel(
    const float* __restrict__ refF,        // [B,256,M]
    const float* __restrict__ refT,        // [B,128,M]
    const float* __restrict__ pf,          // [B,64,N]
    const int4*  __restrict__ wsI,         // [B,N]
    const float4* __restrict__ wsW,        // [B,N]
    float* __restrict__ out)               // [B,320,N] ++ [B,128,N]
{
#pragma clang fp contract(off)
    __shared__ float rowA[MM];             // 16 KB
    __shared__ float rowB[MM];             // 16 KB
    const int tid  = threadIdx.x;
    const int task = blockIdx.x;
    const size_t outT_base = (size_t)BB * (CF + CP) * NN;

    if (task >= NIB) {                     // -------- pf copy blocks --------
        const int t3 = task - NIB;         // 0..31, 4 rows each
        for (int j = 0; j < 4; ++j) {
            const int r  = t3 * 4 + j;
            const int bb = r >> 6;
            const int c  = r & (CP - 1);
            const float4* s4 = (const float4*)(pf + ((size_t)bb * CP + c) * NN);
            float4* d4 = (float4*)(out + ((size_t)bb * (CF + CP) + CF + c) * NN);
            for (int i = tid; i < NN / 4; i += TPB2) d4[i] = s4[i];
        }
        return;                            // block-uniform exit
    }

    const int r0 = task * 2;               // rows r0, r0+1 (same b, same class)
    const float* src0;
    float* dst0;
    int b;
    if (r0 < BB * CF) {                    // interpolated features
        b = r0 >> 8;
        const int c = r0 & (CF - 1);
        src0 = refF + ((size_t)b * CF + c) * MM;
        dst0 = out + ((size_t)b * (CF + CP) + c) * NN;
    } else {                               // interpolated t_embed
        const int r2 = r0 - BB * CF;
        b = r2 >> 7;
        const int c = r2 & (CT - 1);
        src0 = refT + ((size_t)b * CT + c) * MM;
        dst0 = out + outT_base + ((size_t)b * CT + c) * NN;
    }
    const float* src1 = src0 + MM;
    float* dst1 = dst0 + NN;

    for (int i = tid; i < MM / 4; i += TPB2) {
        ((float4*)rowA)[i] = ((const float4*)src0)[i];
        ((float4*)rowB)[i] = ((const float4*)src1)[i];
    }
    __syncthreads();

    const int4*   wi = wsI + (size_t)b * NN;
    const float4* ww = wsW + (size_t)b * NN;

    auto clampi = [](int v) { return v < 0 ? 0 : (v > MM - 1 ? MM - 1 : v); };

    int4   id = wi[tid];
    float4 w  = ww[tid];
    for (int nq = tid; nq < NN; nq += TPB2) {
        const int nq2 = nq + TPB2;
        int4   idn;
        float4 wn;
        if (nq2 < NN) { idn = wi[nq2]; wn = ww[nq2]; }   // prefetch next
        const int a0 = clampi(id.x), a1 = clampi(id.y), a2 = clampi(id.z);
        dst0[nq] = (w.x * rowA[a0] + w.y * rowA[a1]) + w.z * rowA[a2];
        dst1[nq] = (w.x * rowB[a0] + w.y * rowB[a1]) + w.z * rowB[a2];
        id = idn; w = wn;
    }
}

extern "C" void kernel_launch(void* const* d_in, const int* in_sizes, int n_in,
                              void* d_out, int out_size, void* d_ws, size_t ws_size,
                              hipStream_t stream) {
    const float* coords     = (const float*)d_in[0];
    const float* ref_coords = (const float*)d_in[1];
    const float* refF       = (const float*)d_in[2];
    const float* refT       = (const float*)d_in[3];
    const float* pf         = (const float*)d_in[4];
    float* out = (float*)d_out;

    int4*   wsI = (int4*)d_ws;
    float4* wsW = (float4*)((char*)d_ws + (size_t)BB * NN * sizeof(int4));

    hipLaunchKernelGGL(knn_kernel, dim3(NN / NPB1, BB), dim3(TPB1), 0, stream,
                       coords, ref_coords, wsI, wsW);
    hipLaunchKernelGGL(interp_kernel, dim3(NIB + NCB), dim3(TPB2), 0, stream,
                       refF, refT, pf, wsI, wsW, out);
}